// Round 17
// baseline (926.234 us; speedup 1.0000x reference)
//
#include <hip/hip_runtime.h>
#include <hip/hip_bf16.h>
#include <cstdint>
#include <cstddef>

#define TTOK   4096
#define DIM_   2048
#define INTER_ 1408
#define NEXP   16
#define SINTER_ 2816
#define BM 128
#define BN 128
#define BK 64
#define MAXROWS (TTOK*2 + NEXP*256)           /* 12288 padded routed slots (256-pad) */
#define MAXMT128 (MAXROWS/128)                /* 96 per-128 tiles (h13) */
#define MAXMT256 (MAXROWS/256)                /* 48 per-256 tiles (out) */

#define NT_SH_H  ((TTOK/BM) * (SINTER_/BN))   /* 704 shared h13 tiles  */
#define NT_RT_H  (MAXMT128 * (INTER_/BN))     /* 1056 routed h13 tiles */
#define NT_H     (NT_SH_H + NT_RT_H)          /* 1760 */

#define OBM 256
#define OBN 128
#define NT_SH_O  ((TTOK/OBM) * (DIM_/OBN))    /* 256 shared out tiles  */
#define NT_RT_O  (MAXMT256 * (DIM_/OBN))      /* 768 routed out tiles  */
#define NT_O     (NT_SH_O + NT_RT_O)          /* 1024 */

// misc layout (ints): [0..16) counts, [16..32) fill, [32..48) base,
// [48..144) te128, [144..240) tr128, [240..288) te256, [288..336) tr256
#define M_TE   48
#define M_TR   144
#define M_TE2  240
#define M_TR2  288

typedef unsigned short u16;
typedef __attribute__((ext_vector_type(8))) short short8;
typedef __attribute__((ext_vector_type(4))) float f32x4;

#define AS3P(p) ((__attribute__((address_space(3))) void*)(p))
#define AS1P(p) ((const __attribute__((address_space(1))) void*)(p))

__device__ __forceinline__ void gll16(const void* g, void* l) {
    __builtin_amdgcn_global_load_lds(AS1P(g), AS3P(l), 16, 0, 0);
}

__device__ __forceinline__ u16 f2bf(float f) {
    __hip_bfloat16 h = __float2bfloat16(f);
    union { __hip_bfloat16 h; u16 u; } c; c.h = h; return c.u;
}

__device__ __forceinline__ unsigned pk2(float a, float b) {
    unsigned r;
    asm("v_cvt_pk_bf16_f32 %0, %1, %2" : "=v"(r) : "v"(a), "v"(b));
    return r;
}

__device__ __forceinline__ int4 pack8(float4 a, float4 b) {
    int4 r;
    r.x = (int)pk2(a.x, a.y);
    r.y = (int)pk2(a.z, a.w);
    r.z = (int)pk2(b.x, b.y);
    r.w = (int)pk2(b.z, b.w);
    return r;
}

// counted-vmcnt wait + barrier (loads stay in flight across the barrier);
// "memory" clobber pins C++ LDS/global ops relative to the asm (rule #18/#21).
#define WB(NLIT) do { \
    asm volatile("s_waitcnt vmcnt(" #NLIT ")" ::: "memory"); \
    __builtin_amdgcn_s_barrier(); \
    asm volatile("" ::: "memory"); \
} while (0)
// ds_read-complete barrier WITHOUT draining vmcnt (NOT __syncthreads: that
// emits s_waitcnt vmcnt(0) and kills the pipeline)
#define LB() do { \
    asm volatile("s_waitcnt lgkmcnt(0)" ::: "memory"); \
    __builtin_amdgcn_s_barrier(); \
    asm volatile("" ::: "memory"); \
} while (0)

// ---------------- merged conversion + init + out-zero (NO gate: its register
// pressure halved this BW-kernel's occupancy in R16, cvt 222->334 us) ----------------
#define NW8  ((long)NEXP * INTER_ * DIM_ / 8)
#define NSW8 ((long)SINTER_ * DIM_ / 8)
#define NX8  ((long)TTOK * DIM_ / 8)
#define TOT8 (3 * NW8 + 3 * NSW8 + NX8)
#define CVT_BLK 4096

__global__ void cvt_all_kernel(
    const float* __restrict__ w1, const float* __restrict__ w2,
    const float* __restrict__ w3, const float* __restrict__ sw1,
    const float* __restrict__ sw2, const float* __restrict__ sw3,
    const float* __restrict__ x,
    u16* __restrict__ w1b, u16* __restrict__ w2b, u16* __restrict__ w3b,
    u16* __restrict__ sw1b, u16* __restrict__ sw2b, u16* __restrict__ sw3b,
    u16* __restrict__ xb,
    int* __restrict__ perm_rt, float* __restrict__ pw_rt,
    int* __restrict__ zrow,
    float* __restrict__ outz)
{
    const long stride = (long)gridDim.x * 256;
    const long gid = (long)blockIdx.x * 256 + threadIdx.x;

    if (gid < MAXROWS) { perm_rt[gid] = -1; pw_rt[gid] = 0.f; }
    if (gid < 1024)    zrow[gid] = 0;
    for (long i = gid; i < (long)TTOK * DIM_ / 4; i += stride)
        *(float4*)(outz + i * 4) = make_float4(0.f, 0.f, 0.f, 0.f);

    for (long i = gid; i < TOT8; i += stride) {
        const float* s; u16* d; long off;
        if      (i <     NW8)              { s = w1;  d = w1b;  off = i; }
        else if (i < 2 * NW8)              { s = w2;  d = w2b;  off = i - NW8; }
        else if (i < 3 * NW8)              { s = w3;  d = w3b;  off = i - 2 * NW8; }
        else if (i < 3 * NW8 + NSW8)       { s = sw1; d = sw1b; off = i - 3 * NW8; }
        else if (i < 3 * NW8 + 2 * NSW8)   { s = sw2; d = sw2b; off = i - 3 * NW8 - NSW8; }
        else if (i < 3 * NW8 + 3 * NSW8)   { s = sw3; d = sw3b; off = i - 3 * NW8 - 2 * NSW8; }
        else                               { s = x;   d = xb;   off = i - 3 * NW8 - 3 * NSW8; }
        const float4* s4 = (const float4*)(s + off * 8);
        float4 a = s4[0], b = s4[1];
        *(int4*)(d + off * 8) = pack8(a, b);
    }
}

__global__ void gate_kernel(const float* __restrict__ x, const float* __restrict__ gw,
                            int* __restrict__ topi, float* __restrict__ topw,
                            int* __restrict__ misc) {
    int t = blockIdx.x;
    int lane = threadIdx.x;
    const float* xr = x + (size_t)t * DIM_;
    float acc[NEXP];
#pragma unroll
    for (int e = 0; e < NEXP; e++) acc[e] = 0.f;
#pragma unroll
    for (int i = 0; i < 8; i++) {
        int k = i * 256 + lane * 4;
        float4 xv = *(const float4*)(xr + k);
#pragma unroll
        for (int e = 0; e < NEXP; e++) {
            float4 gv = *(const float4*)(gw + (size_t)e * DIM_ + k);
            acc[e] += xv.x * gv.x + xv.y * gv.y + xv.z * gv.z + xv.w * gv.w;
        }
    }
#pragma unroll
    for (int e = 0; e < NEXP; e++) {
        float v = acc[e];
        for (int off = 32; off > 0; off >>= 1) v += __shfl_down(v, off);
        acc[e] = v;
    }
    if (lane == 0) {
        float m = acc[0];
#pragma unroll
        for (int e = 1; e < NEXP; e++) m = fmaxf(m, acc[e]);
        float p[NEXP]; float s = 0.f;
#pragma unroll
        for (int e = 0; e < NEXP; e++) { p[e] = __expf(acc[e] - m); s += p[e]; }
        int i0 = 0; float v0 = p[0];
#pragma unroll
        for (int e = 1; e < NEXP; e++) if (p[e] > v0) { v0 = p[e]; i0 = e; }
        int i1 = -1; float v1 = -1.f;
#pragma unroll
        for (int e = 0; e < NEXP; e++) if (e != i0 && p[e] > v1) { v1 = p[e]; i1 = e; }
        float inv = 1.f / s;
        topi[2 * t] = i0; topi[2 * t + 1] = i1;
        topw[2 * t] = v0 * inv; topw[2 * t + 1] = v1 * inv;
        atomicAdd(&misc[i0], 1);
        atomicAdd(&misc[i1], 1);
    }
}

__global__ void scan_kernel(int* misc) {
    int* counts = misc;
    int* base   = misc + 32;
    int* te  = misc + M_TE;
    int* tr  = misc + M_TR;
    int* te2 = misc + M_TE2;
    int* tr2 = misc + M_TR2;
    int b = 0, tt = 0, tt2 = 0;
    for (int e = 0; e < NEXP; e++) {
        int c = counts[e];
        int nt2 = (c + 255) >> 8;             // pad each expert to 256 rows
        base[e] = b;
        for (int i = 0; i < nt2; i++)     { te2[tt2] = e; tr2[tt2] = b + i * 256; tt2++; }
        for (int i = 0; i < 2 * nt2; i++) { te[tt]   = e; tr[tt]   = b + i * 128; tt++; }
        b += nt2 * 256;
    }
    for (int i = tt;  i < MAXMT128; i++) te[i]  = -1;
    for (int i = tt2; i < MAXMT256; i++) te2[i] = -1;
}

__global__ void scatter_kernel(const int* __restrict__ topi, const float* __restrict__ topw,
                               int* __restrict__ misc, int* __restrict__ perm,
                               float* __restrict__ pw) {
    int t = blockIdx.x * 256 + threadIdx.x;
    if (t >= TTOK) return;
    int* fill = misc + 16;
    int* base = misc + 32;
#pragma unroll
    for (int k = 0; k < 2; k++) {
        int e = topi[2 * t + k];
        int pos = base[e] + atomicAdd(&fill[e], 1);
        perm[pos] = t;
        pw[pos] = topw[2 * t + k];
    }
}

// ---------------- MERGED h13 GEMM (R12/R14 champion structure) ----------------
// bf16, gll16 staging, BK=64, 2 barriers/K-step, dual-B fused.
// Swizzle (verified 0 conflicts): store global chunk (l&7)^(l>>3), read cc^(col&7).
// (256,2) REQUIRED (dual acc; R5 spill at higher occupancy caps).

__global__ __launch_bounds__(256, 2) void gemm_h13_m(
    const u16* __restrict__ Xb,
    const u16* __restrict__ W1b, const u16* __restrict__ W3b,
    u16* __restrict__ HS, u16* __restrict__ HR,
    const int* __restrict__ perm,
    const int* __restrict__ te, const int* __restrict__ tr,
    const u16* __restrict__ zrow,
    int K, int chunk)
{
    const int q = (blockIdx.x & 7) * chunk + (blockIdx.x >> 3);
    if (q >= NT_H) return;
    int im, jn, N, slot0; size_t eoff; u16* H; bool gather;
    if (q < NT_SH_H) {
        im = q % (TTOK / BM); jn = q / (TTOK / BM);
        N = SINTER_; slot0 = im * BM; eoff = (size_t)NEXP * INTER_ * DIM_;
        H = HS; gather = false;
    } else {
        int q2 = q - NT_SH_H;
        im = q2 % MAXMT128; jn = q2 / MAXMT128;
        int e = te[im]; if (e < 0) return;
        slot0 = tr[im]; N = INTER_; eoff = (size_t)e * INTER_ * DIM_;
        H = HR; gather = true;
    }
    const int n0 = jn * BN;
    const u16* W1 = W1b + eoff;
    const u16* W3 = W3b + eoff;

    __shared__ __align__(16) u16 As[BM * BK];
    __shared__ __align__(16) u16 B1s[BM * BK];
    __shared__ __align__(16) u16 B3s[BM * BK];

    const int tid = threadIdx.x;
    const int lane = tid & 63, wid = tid >> 6;
    const int wr = wid >> 1, wc = wid & 1;
    const int col = lane & 15, kg = lane >> 4;

    const int lr8 = lane >> 3;
    const int kb  = ((lane & 7) ^ lr8) * 8;
    const int rB0 = wid * 32 + lr8;
    const u16* gA[4];
#pragma unroll
    for (int i = 0; i < 4; i++) {
        int row = slot0 + rB0 + 8 * i;
        if (gather) {
            int ta = perm[row];
            gA[i] = (ta >= 0 ? Xb + (size_t)ta * K : zrow) + kb;
        } else {
            gA[i] = Xb + (size_t)row * K + kb;
        }
    }
    const u16* g1 = W1 + (size_t)(n0 + rB0) * K + kb;
    const u16* g3 = W3 + (size_t)(n0 + rB0) * K + kb;

    const int ldsI = (wid * 32) * BK;
    const int swr = col & 7;

    f32x4 acc1[4][4] = {};
    f32x4 acc3[4][4] = {};

    for (int k0 = 0; k0 < K; k0 += BK) {
#pragma unroll
        for (int i = 0; i < 4; i++) {
            gll16(gA[i] + k0, As + ldsI + i * 8 * BK);
            gll16(g1 + (size_t)(8 * i) * K + k0, B1s + ldsI + i * 8 * BK);
            gll16(g3 + (size_t)(8 * i) * K + k0, B3s + ldsI + i * 8 * BK);
        }
        __syncthreads();

        short8 a[4][2];
#pragma unroll
        for (int mi = 0; mi < 4; mi++)
#pragma unroll
            for (int t = 0; t < 2; t++) {
                int cc = kg + 4 * t;
                a[mi][t] = *(const short8*)(As + (wr * 64 + mi * 16 + col) * BK + ((cc ^ swr) * 8));
            }
#pragma unroll
        for (int t = 0; t < 2; t++) {
#pragma unroll
            for (int ni = 0; ni < 4; ni++) {
                int cc = kg + 4 * t;
                int off = (wc * 64 + ni * 16 + col) * BK + ((cc ^ swr) * 8);
                short8 v1 = *(const short8*)(B1s + off);
                short8 v3 = *(const short8*)(B3s + off);
#pragma unroll
                for (int mi = 0; mi < 4; mi++) {
                    acc1[mi][ni] = __builtin_amdgcn_mfma_f32_16x16x32_bf16(a[mi][t], v1, acc1[mi][ni], 0, 0, 0);
                    acc3[mi][ni] = __builtin_amdgcn_mfma_f32_16x16x32_bf16(a[mi][t], v3, acc3[mi][ni], 0, 0, 0);
                }
            }
        }
        __syncthreads();
    }

#pragma unroll
    for (int mi = 0; mi < 4; mi++) {
#pragma unroll
        for (int j = 0; j < 4; j++) {
            int row = slot0 + wr * 64 + mi * 16 + kg * 4 + j;
#pragma unroll
            for (int ni = 0; ni < 4; ni++) {
                float v1 = acc1[mi][ni][j];
                float v3 = acc3[mi][ni][j];
                float hv = v1 / (1.f + __expf(-v1)) * v3;
                int c = n0 + wc * 64 + ni * 16 + col;
                H[(size_t)row * N + c] = f2bf(hv);
            }
        }
    }
}

// ---------------- 3-stage pipelined out GEMM (256x128 tile, 512 thr, BK=64) ----------------
// R16-verified: 247 us vs 2-barrier's 293 (-16%). Deep pipeline at K-tile
// granularity: buffers t%3; compute tile t while t+1,t+2 in flight.
// Per tile: {vmcnt(12|6|0)+barrier -> 20 ds_read -> lgkmcnt(0)+raw barrier ->
// ISSUE(t+3 into buf t%3) -> 32 MFMA}. No __syncthreads in loop.
// 8 waves: wr=wid>>2, wcn=wid&3; acc[8][2]=64 regs. LDS 144 KB -> 1 block/CU.

__global__ __launch_bounds__(512, 2) void gemm_out_p(
    const u16* __restrict__ HS, const u16* __restrict__ HR,
    const u16* __restrict__ W2b,
    float* __restrict__ Out,
    const int* __restrict__ perm, const float* __restrict__ pw,
    const int* __restrict__ te2, const int* __restrict__ tr2,
    int chunk)
{
    const int q = (blockIdx.x & 7) * chunk + (blockIdx.x >> 3);
    if (q >= NT_O) return;
    int im, jn, K, slot0; size_t eoff; const u16* A; bool gather;
    if (q < NT_SH_O) {
        im = q % (TTOK / OBM); jn = q / (TTOK / OBM);
        K = SINTER_; slot0 = im * OBM; eoff = (size_t)NEXP * INTER_ * DIM_;
        A = HS; gather = false;
    } else {
        int q2 = q - NT_SH_O;
        im = q2 % MAXMT256; jn = q2 / MAXMT256;
        int e = te2[im]; if (e < 0) return;
        slot0 = tr2[im]; K = INTER_; eoff = (size_t)e * INTER_ * DIM_;
        A = HR; gather = true;
    }
    const int n0 = jn * OBN;
    const u16* W2 = W2b + eoff;

    __shared__ __align__(16) u16 As3[3 * OBM * BK];   // 3 x 32 KB
    __shared__ __align__(16) u16 Bs3[3 * OBN * BK];   // 3 x 16 KB

    const int tid = threadIdx.x;
    const int lane = tid & 63, wid = tid >> 6;
    const int wr = wid >> 2, wcn = wid & 3;
    const int col = lane & 15, kg = lane >> 4;

    const int lr8 = lane >> 3;
    const int kb  = ((lane & 7) ^ lr8) * 8;
    const u16* gA = A + (size_t)(slot0 + wid * 32 + lr8) * K + kb;
    const u16* gB = W2 + (size_t)(n0 + wid * 16 + lr8) * K + kb;
    const int ldsA = (wid * 32) * BK;
    const int ldsB = (wid * 16) * BK;
    const int swr = col & 7;

    f32x4 acc[8][2] = {};

    auto ISSUE = [&](int t) {
        const int ab = (t % 3) * OBM * BK;
        const int bb = (t % 3) * OBN * BK;
        const int ko = t * BK;
#pragma unroll
        for (int i = 0; i < 4; i++)
            gll16(gA + (size_t)(8 * i) * K + ko, As3 + ab + ldsA + i * 8 * BK);
#pragma unroll
        for (int i = 0; i < 2; i++)
            gll16(gB + (size_t)(8 * i) * K + ko, Bs3 + bb + ldsB + i * 8 * BK);
    };

    const int nt = K / BK;
    ISSUE(0); ISSUE(1); ISSUE(2);

    for (int t = 0; t < nt; ++t) {
        if (t + 2 < nt)      WB(12);
        else if (t + 1 < nt) WB(6);
        else                 WB(0);

        const u16* Ac = As3 + (t % 3) * OBM * BK;
        const u16* Bc = Bs3 + (t % 3) * OBN * BK;

        short8 a[8][2], b[2][2];
#pragma unroll
        for (int mi = 0; mi < 8; mi++)
#pragma unroll
            for (int kk = 0; kk < 2; kk++) {
                int cc = kg + 4 * kk;
                a[mi][kk] = *(const short8*)(Ac + (wr * 128 + mi * 16 + col) * BK + ((cc ^ swr) * 8));
            }
#pragma unroll
        for (int ni = 0; ni < 2; ni++)
#pragma unroll
            for (int kk = 0; kk < 2; kk++) {
                int cc = kg + 4 * kk;
                b[ni][kk] = *(const short8*)(Bc + (wcn * 32 + ni * 16 + col) * BK + ((cc ^ swr) * 8));
            }

        LB();                         // all waves done reading buf t%3
        if (t + 3 < nt) ISSUE(t + 3); // reuse buf t%3; lands >=2 phases later

#pragma unroll
        for (int kk = 0; kk < 2; kk++)
#pragma unroll
            for (int ni = 0; ni < 2; ni++)
#pragma unroll
                for (int mi = 0; mi < 8; mi++)
                    acc[mi][ni] = __builtin_amdgcn_mfma_f32_16x16x32_bf16(a[mi][kk], b[ni][kk], acc[mi][ni], 0, 0, 0);
    }

#pragma unroll
    for (int mi = 0; mi < 8; mi++) {
#pragma unroll
        for (int j = 0; j < 4; j++) {
            int slot = slot0 + wr * 128 + mi * 16 + kg * 4 + j;
            int token; float w;
            if (gather) {
                token = perm[slot];
                if (token < 0) continue;
                w = pw[slot];
            } else {
                token = slot;
                w = 1.f;
            }
#pragma unroll
            for (int ni = 0; ni < 2; ni++) {
                int c = n0 + wcn * 32 + ni * 16 + col;
                atomicAdd(&Out[(size_t)token * DIM_ + c], acc[mi][ni][j] * w);
            }
        }
    }
}

// ---------------- launch ----------------

extern "C" void kernel_launch(void* const* d_in, const int* in_sizes, int n_in,
                              void* d_out, int out_size, void* d_ws, size_t ws_size,
                              hipStream_t stream) {
    (void)in_sizes; (void)n_in; (void)out_size; (void)ws_size;
    const float* x   = (const float*)d_in[0];
    const float* gw  = (const float*)d_in[1];
    const float* w1  = (const float*)d_in[2];
    const float* w2  = (const float*)d_in[3];
    const float* w3  = (const float*)d_in[4];
    const float* sw1 = (const float*)d_in[5];
    const float* sw2 = (const float*)d_in[6];
    const float* sw3 = (const float*)d_in[7];
    float* out = (float*)d_out;

    char* ws = (char*)d_ws;
    size_t off = 0;
    auto take = [&](size_t bytes) -> void* {
        void* p = ws + off;
        off += (bytes + 255) & ~(size_t)255;
        return p;
    };
    u16*   xb      = (u16*)take((size_t)TTOK * DIM_ * 2);
    u16*   hbufS   = (u16*)take((size_t)TTOK * SINTER_ * 2);
    u16*   hbufR   = (u16*)take((size_t)MAXROWS * INTER_ * 2);
    int*   perm_rt = (int*)take((size_t)MAXROWS * 4);
    float* pw_rt   = (float*)take((size_t)MAXROWS * 4);
    int*   topi    = (int*)take((size_t)TTOK * 2 * 4);
    float* topw    = (float*)take((size_t)TTOK * 2 * 4);
    int*   misc    = (int*)take(2048);
    int*   zrow    = (int*)take(4096);
    const size_t nW  = (size_t)NEXP * INTER_ * DIM_;
    const size_t nSW = (size_t)SINTER_ * DIM_;
    // ADJACENCY REQUIRED: each w*b immediately followed by its sw*b
    // (sizes are 256-multiples -> no padding) so eIdx=16 addresses shared.
    u16* w1b  = (u16*)take(nW * 2);
    u16* sw1b = (u16*)take(nSW * 2);
    u16* w3b  = (u16*)take(nW * 2);
    u16* sw3b = (u16*)take(nSW * 2);
    u16* w2b  = (u16*)take(nW * 2);
    u16* sw2b = (u16*)take(nSW * 2);

    // zero gate counters before gate's atomics
    hipMemsetAsync(misc, 0, 128, stream);

    // 1) merged conversion + init + out-zero (BW-bound, VGPR-lean)
    cvt_all_kernel<<<CVT_BLK, 256, 0, stream>>>(
        w1, w2, w3, sw1, sw2, sw3, x,
        w1b, w2b, w3b, sw1b, sw2b, sw3b, xb,
        perm_rt, pw_rt, zrow, out);
    // 2) gate (separate: register-heavy; folding it into cvt cost -31% occ, R16)
    gate_kernel<<<TTOK, 64, 0, stream>>>(x, gw, topi, topw, misc);
    // 3) scan / 4) scatter
    scan_kernel<<<1, 1, 0, stream>>>(misc);
    scatter_kernel<<<TTOK / 256, 256, 0, stream>>>(topi, topw, misc, perm_rt, pw_rt);

    // 5) merged h13 (shared 704 + routed up-to-1056 tiles)
    gemm_h13_m<<<NT_H, 256, 0, stream>>>(
        xb, w1b, w3b, hbufS, hbufR, perm_rt, misc + M_TE, misc + M_TR,
        (const u16*)zrow, DIM_, NT_H / 8);

    // 6) 3-stage pipelined out (shared 256 + routed up-to-768 tiles), atomic
    gemm_out_p<<<NT_O, 512, 0, stream>>>(
        hbufS, hbufR, w2b, out, perm_rt, pw_rt, misc + M_TE2, misc + M_TR2,
        NT_O / 8);
}

// Round 18
// 859.583 us; speedup vs baseline: 1.0775x; 1.0775x over previous
//
#include <hip/hip_runtime.h>
#include <hip/hip_bf16.h>
#include <cstdint>
#include <cstddef>

#define TTOK   4096
#define DIM_   2048
#define INTER_ 1408
#define NEXP   16
#define SINTER_ 2816
#define BM 128
#define BN 128
#define BK 64
#define MAXROWS (TTOK*2 + NEXP*BM)            /* 10240 padded routed slots (128-pad) */
#define MAXMT   (TTOK*2/BM + NEXP)            /* 80 worst-case per-128 M tiles */

#define NT_SH_H  ((TTOK/BM) * (SINTER_/BN))   /* 704 shared h13 tiles  */
#define NT_RT_H  (MAXMT * (INTER_/BN))        /* 880 routed h13 tiles  */
#define NT_H     (NT_SH_H + NT_RT_H)          /* 1584 */

#define NT_SH_O  ((TTOK/BM) * (DIM_/256))     /* 256 shared out tiles (128x256) */
#define NT_RT_O  (MAXMT * (DIM_/256))         /* 640 routed out tiles  */
#define NT_O     (NT_SH_O + NT_RT_O)          /* 896 */

// misc layout (ints): [0..16) counts, [16..32) fill, [32..48) base,
//                     [48..128) tile_expert, [128..208) tile_row0
#define M_TE   48
#define M_TR   128

typedef unsigned short u16;
typedef __attribute__((ext_vector_type(8))) short short8;
typedef __attribute__((ext_vector_type(4))) float f32x4;

#define AS3P(p) ((__attribute__((address_space(3))) void*)(p))
#define AS1P(p) ((const __attribute__((address_space(1))) void*)(p))

__device__ __forceinline__ void gll16(const void* g, void* l) {
    __builtin_amdgcn_global_load_lds(AS1P(g), AS3P(l), 16, 0, 0);
}

__device__ __forceinline__ u16 f2bf(float f) {
    __hip_bfloat16 h = __float2bfloat16(f);
    union { __hip_bfloat16 h; u16 u; } c; c.h = h; return c.u;
}

__device__ __forceinline__ unsigned pk2(float a, float b) {
    unsigned r;
    asm("v_cvt_pk_bf16_f32 %0, %1, %2" : "=v"(r) : "v"(a), "v"(b));
    return r;
}

__device__ __forceinline__ int4 pack8(float4 a, float4 b) {
    int4 r;
    r.x = (int)pk2(a.x, a.y);
    r.y = (int)pk2(a.z, a.w);
    r.z = (int)pk2(b.x, b.y);
    r.w = (int)pk2(b.z, b.w);
    return r;
}

// ---------------- merged conversion + init + out-zero (NO gate: R16 showed
// gate's registers halve this BW-kernel's occupancy; keep VGPR-lean) ----------------
#define NW8  ((long)NEXP * INTER_ * DIM_ / 8)
#define NSW8 ((long)SINTER_ * DIM_ / 8)
#define NX8  ((long)TTOK * DIM_ / 8)
#define TOT8 (3 * NW8 + 3 * NSW8 + NX8)
#define CVT_BLK 4096

__global__ void cvt_all_kernel(
    const float* __restrict__ w1, const float* __restrict__ w2,
    const float* __restrict__ w3, const float* __restrict__ sw1,
    const float* __restrict__ sw2, const float* __restrict__ sw3,
    const float* __restrict__ x,
    u16* __restrict__ w1b, u16* __restrict__ w2b, u16* __restrict__ w3b,
    u16* __restrict__ sw1b, u16* __restrict__ sw2b, u16* __restrict__ sw3b,
    u16* __restrict__ xb,
    int* __restrict__ perm_rt, float* __restrict__ pw_rt,
    int* __restrict__ zrow,
    float* __restrict__ outz)
{
    const long stride = (long)gridDim.x * 256;
    const long gid = (long)blockIdx.x * 256 + threadIdx.x;

    if (gid < MAXROWS) { perm_rt[gid] = -1; pw_rt[gid] = 0.f; }
    if (gid < 1024)    zrow[gid] = 0;
    for (long i = gid; i < (long)TTOK * DIM_ / 4; i += stride)
        *(float4*)(outz + i * 4) = make_float4(0.f, 0.f, 0.f, 0.f);

    for (long i = gid; i < TOT8; i += stride) {
        const float* s; u16* d; long off;
        if      (i <     NW8)              { s = w1;  d = w1b;  off = i; }
        else if (i < 2 * NW8)              { s = w2;  d = w2b;  off = i - NW8; }
        else if (i < 3 * NW8)              { s = w3;  d = w3b;  off = i - 2 * NW8; }
        else if (i < 3 * NW8 + NSW8)       { s = sw1; d = sw1b; off = i - 3 * NW8; }
        else if (i < 3 * NW8 + 2 * NSW8)   { s = sw2; d = sw2b; off = i - 3 * NW8 - NSW8; }
        else if (i < 3 * NW8 + 3 * NSW8)   { s = sw3; d = sw3b; off = i - 3 * NW8 - 2 * NSW8; }
        else                               { s = x;   d = xb;   off = i - 3 * NW8 - 3 * NSW8; }
        const float4* s4 = (const float4*)(s + off * 8);
        float4 a = s4[0], b = s4[1];
        *(int4*)(d + off * 8) = pack8(a, b);
    }
}

__global__ void gate_kernel(const float* __restrict__ x, const float* __restrict__ gw,
                            int* __restrict__ topi, float* __restrict__ topw,
                            int* __restrict__ misc) {
    int t = blockIdx.x;
    int lane = threadIdx.x;
    const float* xr = x + (size_t)t * DIM_;
    float acc[NEXP];
#pragma unroll
    for (int e = 0; e < NEXP; e++) acc[e] = 0.f;
#pragma unroll
    for (int i = 0; i < 8; i++) {
        int k = i * 256 + lane * 4;
        float4 xv = *(const float4*)(xr + k);
#pragma unroll
        for (int e = 0; e < NEXP; e++) {
            float4 gv = *(const float4*)(gw + (size_t)e * DIM_ + k);
            acc[e] += xv.x * gv.x + xv.y * gv.y + xv.z * gv.z + xv.w * gv.w;
        }
    }
#pragma unroll
    for (int e = 0; e < NEXP; e++) {
        float v = acc[e];
        for (int off = 32; off > 0; off >>= 1) v += __shfl_down(v, off);
        acc[e] = v;
    }
    if (lane == 0) {
        float m = acc[0];
#pragma unroll
        for (int e = 1; e < NEXP; e++) m = fmaxf(m, acc[e]);
        float p[NEXP]; float s = 0.f;
#pragma unroll
        for (int e = 0; e < NEXP; e++) { p[e] = __expf(acc[e] - m); s += p[e]; }
        int i0 = 0; float v0 = p[0];
#pragma unroll
        for (int e = 1; e < NEXP; e++) if (p[e] > v0) { v0 = p[e]; i0 = e; }
        int i1 = -1; float v1 = -1.f;
#pragma unroll
        for (int e = 0; e < NEXP; e++) if (e != i0 && p[e] > v1) { v1 = p[e]; i1 = e; }
        float inv = 1.f / s;
        topi[2 * t] = i0; topi[2 * t + 1] = i1;
        topw[2 * t] = v0 * inv; topw[2 * t + 1] = v1 * inv;
        atomicAdd(&misc[i0], 1);
        atomicAdd(&misc[i1], 1);
    }
}

__global__ void scan_kernel(int* misc) {
    int* counts = misc;
    int* base   = misc + 32;
    int* te     = misc + M_TE;
    int* tr     = misc + M_TR;
    int b = 0, tt = 0;
    for (int e = 0; e < NEXP; e++) {
        int c = counts[e];
        int nt = (c + BM - 1) >> 7;
        base[e] = b;
        for (int i = 0; i < nt; i++) { te[tt] = e; tr[tt] = b + i * BM; tt++; }
        b += nt * BM;
    }
    for (int i = tt; i < MAXMT; i++) te[i] = -1;
}

__global__ void scatter_kernel(const int* __restrict__ topi, const float* __restrict__ topw,
                               int* __restrict__ misc, int* __restrict__ perm,
                               float* __restrict__ pw) {
    int t = blockIdx.x * 256 + threadIdx.x;
    if (t >= TTOK) return;
    int* fill = misc + 16;
    int* base = misc + 32;
#pragma unroll
    for (int k = 0; k < 2; k++) {
        int e = topi[2 * t + k];
        int pos = base[e] + atomicAdd(&fill[e], 1);
        perm[pos] = t;
        pw[pos] = topw[2 * t + k];
    }
}

// ---------------- MERGED h13 GEMM (R12/R14 champion structure, unchanged) ----------------
// bf16, gll16 staging, BK=64, 2 barriers/K-step, dual-B fused (48 MFMA/barrier).
// Swizzle (verified 0 conflicts): store global chunk (l&7)^(l>>3), read cc^(col&7).
// (256,2) REQUIRED (dual acc; R5 spill at higher occupancy caps).

__global__ __launch_bounds__(256, 2) void gemm_h13_m(
    const u16* __restrict__ Xb,
    const u16* __restrict__ W1b, const u16* __restrict__ W3b,
    u16* __restrict__ HS, u16* __restrict__ HR,
    const int* __restrict__ perm,
    const int* __restrict__ te, const int* __restrict__ tr,
    const u16* __restrict__ zrow,
    int K, int chunk)
{
    const int q = (blockIdx.x & 7) * chunk + (blockIdx.x >> 3);
    if (q >= NT_H) return;
    int im, jn, N, slot0; size_t eoff; u16* H; bool gather;
    if (q < NT_SH_H) {
        im = q % (TTOK / BM); jn = q / (TTOK / BM);
        N = SINTER_; slot0 = im * BM; eoff = (size_t)NEXP * INTER_ * DIM_;
        H = HS; gather = false;
    } else {
        int q2 = q - NT_SH_H;
        im = q2 % MAXMT; jn = q2 / MAXMT;
        int e = te[im]; if (e < 0) return;
        slot0 = tr[im]; N = INTER_; eoff = (size_t)e * INTER_ * DIM_;
        H = HR; gather = true;
    }
    const int n0 = jn * BN;
    const u16* W1 = W1b + eoff;
    const u16* W3 = W3b + eoff;

    __shared__ __align__(16) u16 As[BM * BK];
    __shared__ __align__(16) u16 B1s[BM * BK];
    __shared__ __align__(16) u16 B3s[BM * BK];

    const int tid = threadIdx.x;
    const int lane = tid & 63, wid = tid >> 6;
    const int wr = wid >> 1, wc = wid & 1;
    const int col = lane & 15, kg = lane >> 4;

    const int lr8 = lane >> 3;
    const int kb  = ((lane & 7) ^ lr8) * 8;
    const int rB0 = wid * 32 + lr8;
    const u16* gA[4];
#pragma unroll
    for (int i = 0; i < 4; i++) {
        int row = slot0 + rB0 + 8 * i;
        if (gather) {
            int ta = perm[row];
            gA[i] = (ta >= 0 ? Xb + (size_t)ta * K : zrow) + kb;
        } else {
            gA[i] = Xb + (size_t)row * K + kb;
        }
    }
    const u16* g1 = W1 + (size_t)(n0 + rB0) * K + kb;
    const u16* g3 = W3 + (size_t)(n0 + rB0) * K + kb;

    const int ldsI = (wid * 32) * BK;
    const int swr = col & 7;

    f32x4 acc1[4][4] = {};
    f32x4 acc3[4][4] = {};

    for (int k0 = 0; k0 < K; k0 += BK) {
#pragma unroll
        for (int i = 0; i < 4; i++) {
            gll16(gA[i] + k0, As + ldsI + i * 8 * BK);
            gll16(g1 + (size_t)(8 * i) * K + k0, B1s + ldsI + i * 8 * BK);
            gll16(g3 + (size_t)(8 * i) * K + k0, B3s + ldsI + i * 8 * BK);
        }
        __syncthreads();

        short8 a[4][2];
#pragma unroll
        for (int mi = 0; mi < 4; mi++)
#pragma unroll
            for (int t = 0; t < 2; t++) {
                int cc = kg + 4 * t;
                a[mi][t] = *(const short8*)(As + (wr * 64 + mi * 16 + col) * BK + ((cc ^ swr) * 8));
            }
#pragma unroll
        for (int t = 0; t < 2; t++) {
#pragma unroll
            for (int ni = 0; ni < 4; ni++) {
                int cc = kg + 4 * t;
                int off = (wc * 64 + ni * 16 + col) * BK + ((cc ^ swr) * 8);
                short8 v1 = *(const short8*)(B1s + off);
                short8 v3 = *(const short8*)(B3s + off);
#pragma unroll
                for (int mi = 0; mi < 4; mi++) {
                    acc1[mi][ni] = __builtin_amdgcn_mfma_f32_16x16x32_bf16(a[mi][t], v1, acc1[mi][ni], 0, 0, 0);
                    acc3[mi][ni] = __builtin_amdgcn_mfma_f32_16x16x32_bf16(a[mi][t], v3, acc3[mi][ni], 0, 0, 0);
                }
            }
        }
        __syncthreads();
    }

#pragma unroll
    for (int mi = 0; mi < 4; mi++) {
#pragma unroll
        for (int j = 0; j < 4; j++) {
            int row = slot0 + wr * 64 + mi * 16 + kg * 4 + j;
#pragma unroll
            for (int ni = 0; ni < 4; ni++) {
                float v1 = acc1[mi][ni][j];
                float v3 = acc3[mi][ni][j];
                float hv = v1 / (1.f + __expf(-v1)) * v3;
                int c = n0 + wc * 64 + ni * 16 + col;
                H[(size_t)row * N + c] = f2bf(hv);
            }
        }
    }
}

// ---------------- DUAL-PANEL out GEMM (h13's exact loop shape) ----------------
// Block = 128 slots x 256 out-cols; B1s/B3s = W2 col-panels [n0,n0+128) and
// [n0+128,n0+256). Same staging, same swizzle, same 48-MFMA-per-barrier dual-acc
// loop as h13 (proven 750 TF) — only the epilogue differs (atomicAdd both
// panels onto pre-zeroed Out; shared w=1, routed w=pw). (256,2) per R5 rule.

__global__ __launch_bounds__(256, 2) void gemm_out_d(
    const u16* __restrict__ HS, const u16* __restrict__ HR,
    const u16* __restrict__ W2b,
    float* __restrict__ Out,
    const int* __restrict__ perm, const float* __restrict__ pw,
    const int* __restrict__ te, const int* __restrict__ tr,
    int chunk)
{
    const int q = (blockIdx.x & 7) * chunk + (blockIdx.x >> 3);
    if (q >= NT_O) return;
    int im, jn, K, slot0; size_t eoff; const u16* A; bool gather;
    if (q < NT_SH_O) {
        im = q % (TTOK / BM); jn = q / (TTOK / BM);
        K = SINTER_; slot0 = im * BM; eoff = (size_t)NEXP * INTER_ * DIM_;
        A = HS; gather = false;
    } else {
        int q2 = q - NT_SH_O;
        im = q2 % MAXMT; jn = q2 / MAXMT;
        int e = te[im]; if (e < 0) return;
        slot0 = tr[im]; K = INTER_; eoff = (size_t)e * INTER_ * DIM_;
        A = HR; gather = true;
    }
    const int n0 = jn * 256;
    const u16* W2 = W2b + eoff;

    __shared__ __align__(16) u16 As[BM * BK];
    __shared__ __align__(16) u16 B1s[BM * BK];
    __shared__ __align__(16) u16 B3s[BM * BK];

    const int tid = threadIdx.x;
    const int lane = tid & 63, wid = tid >> 6;
    const int wr = wid >> 1, wc = wid & 1;
    const int col = lane & 15, kg = lane >> 4;

    const int lr8 = lane >> 3;
    const int kb  = ((lane & 7) ^ lr8) * 8;
    const int rB0 = wid * 32 + lr8;
    const u16* gA = A + (size_t)(slot0 + rB0) * K + kb;
    const u16* g1 = W2 + (size_t)(n0 + rB0) * K + kb;          // panel 0
    const u16* g3 = W2 + (size_t)(n0 + 128 + rB0) * K + kb;    // panel 1

    const int ldsI = (wid * 32) * BK;
    const int swr = col & 7;

    f32x4 acc1[4][4] = {};
    f32x4 acc3[4][4] = {};

    for (int k0 = 0; k0 < K; k0 += BK) {
#pragma unroll
        for (int i = 0; i < 4; i++) {
            gll16(gA + (size_t)(8 * i) * K + k0, As + ldsI + i * 8 * BK);
            gll16(g1 + (size_t)(8 * i) * K + k0, B1s + ldsI + i * 8 * BK);
            gll16(g3 + (size_t)(8 * i) * K + k0, B3s + ldsI + i * 8 * BK);
        }
        __syncthreads();

        short8 a[4][2];
#pragma unroll
        for (int mi = 0; mi < 4; mi++)
#pragma unroll
            for (int t = 0; t < 2; t++) {
                int cc = kg + 4 * t;
                a[mi][t] = *(const short8*)(As + (wr * 64 + mi * 16 + col) * BK + ((cc ^ swr) * 8));
            }
#pragma unroll
        for (int t = 0; t < 2; t++) {
#pragma unroll
            for (int ni = 0; ni < 4; ni++) {
                int cc = kg + 4 * t;
                int off = (wc * 64 + ni * 16 + col) * BK + ((cc ^ swr) * 8);
                short8 v1 = *(const short8*)(B1s + off);
                short8 v3 = *(const short8*)(B3s + off);
#pragma unroll
                for (int mi = 0; mi < 4; mi++) {
                    acc1[mi][ni] = __builtin_amdgcn_mfma_f32_16x16x32_bf16(a[mi][t], v1, acc1[mi][ni], 0, 0, 0);
                    acc3[mi][ni] = __builtin_amdgcn_mfma_f32_16x16x32_bf16(a[mi][t], v3, acc3[mi][ni], 0, 0, 0);
                }
            }
        }
        __syncthreads();
    }

#pragma unroll
    for (int mi = 0; mi < 4; mi++) {
#pragma unroll
        for (int j = 0; j < 4; j++) {
            int slot = slot0 + wr * 64 + mi * 16 + kg * 4 + j;
            int token; float w;
            if (gather) {
                token = perm[slot];
                if (token < 0) continue;
                w = pw[slot];
            } else {
                token = slot;
                w = 1.f;
            }
            float* orow = Out + (size_t)token * DIM_;
#pragma unroll
            for (int ni = 0; ni < 4; ni++) {
                int c = n0 + wc * 64 + ni * 16 + col;
                atomicAdd(&orow[c],       acc1[mi][ni][j] * w);
                atomicAdd(&orow[c + 128], acc3[mi][ni][j] * w);
            }
        }
    }
}

// ---------------- launch ----------------

extern "C" void kernel_launch(void* const* d_in, const int* in_sizes, int n_in,
                              void* d_out, int out_size, void* d_ws, size_t ws_size,
                              hipStream_t stream) {
    (void)in_sizes; (void)n_in; (void)out_size; (void)ws_size;
    const float* x   = (const float*)d_in[0];
    const float* gw  = (const float*)d_in[1];
    const float* w1  = (const float*)d_in[2];
    const float* w2  = (const float*)d_in[3];
    const float* w3  = (const float*)d_in[4];
    const float* sw1 = (const float*)d_in[5];
    const float* sw2 = (const float*)d_in[6];
    const float* sw3 = (const float*)d_in[7];
    float* out = (float*)d_out;

    char* ws = (char*)d_ws;
    size_t off = 0;
    auto take = [&](size_t bytes) -> void* {
        void* p = ws + off;
        off += (bytes + 255) & ~(size_t)255;
        return p;
    };
    u16*   xb      = (u16*)take((size_t)TTOK * DIM_ * 2);
    u16*   hbufS   = (u16*)take((size_t)TTOK * SINTER_ * 2);
    u16*   hbufR   = (u16*)take((size_t)MAXROWS * INTER_ * 2);
    int*   perm_rt = (int*)take((size_t)MAXROWS * 4);
    float* pw_rt   = (float*)take((size_t)MAXROWS * 4);
    int*   topi    = (int*)take((size_t)TTOK * 2 * 4);
    float* topw    = (float*)take((size_t)TTOK * 2 * 4);
    int*   misc    = (int*)take(2048);
    int*   zrow    = (int*)take(4096);
    const size_t nW  = (size_t)NEXP * INTER_ * DIM_;
    const size_t nSW = (size_t)SINTER_ * DIM_;
    // ADJACENCY REQUIRED: each w*b immediately followed by its sw*b
    // (sizes are 256-multiples -> no padding) so eIdx=16 addresses shared.
    u16* w1b  = (u16*)take(nW * 2);
    u16* sw1b = (u16*)take(nSW * 2);
    u16* w3b  = (u16*)take(nW * 2);
    u16* sw3b = (u16*)take(nSW * 2);
    u16* w2b  = (u16*)take(nW * 2);
    u16* sw2b = (u16*)take(nSW * 2);

    // zero gate counters before gate's atomics
    hipMemsetAsync(misc, 0, 128, stream);

    // 1) merged conversion + init + out-zero (BW-bound, VGPR-lean)
    cvt_all_kernel<<<CVT_BLK, 256, 0, stream>>>(
        w1, w2, w3, sw1, sw2, sw3, x,
        w1b, w2b, w3b, sw1b, sw2b, sw3b, xb,
        perm_rt, pw_rt, zrow, out);
    // 2) gate (separate kernel: folding into cvt cost -31% occupancy, R16)
    gate_kernel<<<TTOK, 64, 0, stream>>>(x, gw, topi, topw, misc);
    // 3) scan / 4) scatter
    scan_kernel<<<1, 1, 0, stream>>>(misc);
    scatter_kernel<<<TTOK / 256, 256, 0, stream>>>(topi, topw, misc, perm_rt, pw_rt);

    // 5) merged h13 (shared 704 + routed up-to-880 tiles)
    gemm_h13_m<<<NT_H, 256, 0, stream>>>(
        xb, w1b, w3b, hbufS, hbufR, perm_rt, misc + M_TE, misc + M_TR,
        (const u16*)zrow, DIM_, NT_H / 8);

    // 6) dual-panel out (shared 256 + routed up-to-640 tiles), atomic
    gemm_out_d<<<NT_O, 256, 0, stream>>>(
        hbufS, hbufR, w2b, out, perm_rt, pw_rt, misc + M_TE, misc + M_TR,
        NT_O / 8);
}